// Round 1
// baseline (51.853 us; speedup 1.0000x reference)
//
#include <hip/hip_runtime.h>

#define NS 50
#define B_DIM 8192
#define D_DIM 64
#define BD (B_DIM * D_DIM)
#define BLOCK 256

__global__ __launch_bounds__(BLOCK) void energy_score_kernel(
    const float* __restrict__ mean,
    const float* __restrict__ variance,
    const float* __restrict__ noise,
    const float* __restrict__ target,
    float* __restrict__ out) {

    const int idx = blockIdx.x * BLOCK + threadIdx.x;

    const float m = mean[idx];
    const float v = variance[idx];
    const float t = target[idx];
    const float sd = sqrtf(v + 1e-6f);

    // Build samples in registers (static indices only -> stays in VGPRs)
    float s[NS];
    float first = 0.0f;
    const float* np = noise + idx;
    #pragma unroll
    for (int k = 0; k < NS; ++k) {
        float nz = np[(size_t)k * BD];
        s[k] = fmaf(nz, sd, m);
        first += fabsf(s[k] - t);
    }

    // Pairwise sum_{i<j} |s_i - s_j|  (== coef-weighted sorted sum identity)
    float pair = 0.0f;
    #pragma unroll
    for (int i = 0; i < NS; ++i) {
        #pragma unroll
        for (int j = i + 1; j < NS; ++j) {
            pair += fabsf(s[i] - s[j]);
        }
    }

    // energy = first/NS - (BETA/2) * pair / (NS*(NS-1)/2), BETA = 1
    float e = first * (1.0f / NS) - 0.5f * pair * (1.0f / 1225.0f);
    // pre-scale for global mean
    e *= (1.0f / (float)BD);

    // 64-lane wave reduction
    #pragma unroll
    for (int off = 32; off > 0; off >>= 1)
        e += __shfl_down(e, off, 64);

    __shared__ float wsum[BLOCK / 64];
    const int lane = threadIdx.x & 63;
    const int wid  = threadIdx.x >> 6;
    if (lane == 0) wsum[wid] = e;
    __syncthreads();

    if (threadIdx.x == 0) {
        float bs = 0.0f;
        #pragma unroll
        for (int w = 0; w < BLOCK / 64; ++w) bs += wsum[w];
        atomicAdd(out, bs);
    }
}

extern "C" void kernel_launch(void* const* d_in, const int* in_sizes, int n_in,
                              void* d_out, int out_size, void* d_ws, size_t ws_size,
                              hipStream_t stream) {
    const float* mean     = (const float*)d_in[0];
    const float* variance = (const float*)d_in[1];
    const float* noise    = (const float*)d_in[2];
    const float* target   = (const float*)d_in[3];
    float* out = (float*)d_out;

    // d_out is poisoned before timing and not re-zeroed between replays.
    hipMemsetAsync(out, 0, sizeof(float), stream);

    const int grid = BD / BLOCK;  // 2048 blocks
    energy_score_kernel<<<grid, BLOCK, 0, stream>>>(mean, variance, noise, target, out);
}

// Round 2
// 48.173 us; speedup vs baseline: 1.0764x; 1.0764x over previous
//
#include <hip/hip_runtime.h>
#include <float.h>

#define NS 50
#define NP 64              // padded to power of two for bitonic network
#define B_DIM 8192
#define D_DIM 64
#define BD (B_DIM * D_DIM)
#define BLOCK 256

__global__ __launch_bounds__(BLOCK) void energy_score_kernel(
    const float* __restrict__ mean,
    const float* __restrict__ variance,
    const float* __restrict__ noise,
    const float* __restrict__ target,
    float* __restrict__ out) {

    const int idx = blockIdx.x * BLOCK + threadIdx.x;

    const float m = mean[idx];
    const float v = variance[idx];
    const float t = target[idx];
    const float sd = sqrtf(v + 1e-6f);

    // Build samples in registers; pad to 64 with FLT_MAX (sorts to the top,
    // excluded from the coefficient sum). Static indices only -> VGPRs.
    float s[NP];
    float f0 = 0.0f, f1 = 0.0f;   // first-term: 2 accumulator chains
    const float* np_ = noise + idx;
    #pragma unroll
    for (int k = 0; k < NS; ++k) {
        float nz = np_[(size_t)k * BD];
        s[k] = fmaf(nz, sd, m);
        if (k & 1) f1 += fabsf(s[k] - t);
        else       f0 += fabsf(s[k] - t);
    }
    #pragma unroll
    for (int k = NS; k < NP; ++k) s[k] = FLT_MAX;

    // Bitonic sort network, 64 elements, fully unrolled (all indices and
    // directions are compile-time constants -> pure min/max, no cndmask).
    #pragma unroll
    for (int k = 2; k <= NP; k <<= 1) {
        #pragma unroll
        for (int j = k >> 1; j > 0; j >>= 1) {
            #pragma unroll
            for (int i = 0; i < NP; ++i) {
                const int l = i ^ j;
                if (l > i) {
                    const bool up = ((i & k) == 0);
                    float a = s[i], b = s[l];
                    float lo = fminf(a, b);
                    float hi = fmaxf(a, b);
                    s[i] = up ? lo : hi;   // compile-time select
                    s[l] = up ? hi : lo;
                }
            }
        }
    }

    // sum_{i<j}|s_i-s_j| == sum_k (2k-(n-1)) * sorted_k  (low 50 entries)
    float p0 = 0.0f, p1 = 0.0f;
    #pragma unroll
    for (int k = 0; k < NS; ++k) {
        const float c = (float)(2 * k - (NS - 1));
        if (k & 1) p1 = fmaf(c, s[k], p1);
        else       p0 = fmaf(c, s[k], p0);
    }

    // energy = first/NS - 0.5 * pair / (NS*(NS-1)/2); pre-scale by 1/BD
    float e = (f0 + f1) * (1.0f / NS) - (p0 + p1) * (1.0f / 2450.0f);
    e *= (1.0f / (float)BD);

    // 64-lane wave reduction
    #pragma unroll
    for (int off = 32; off > 0; off >>= 1)
        e += __shfl_down(e, off, 64);

    __shared__ float wsum[BLOCK / 64];
    const int lane = threadIdx.x & 63;
    const int wid  = threadIdx.x >> 6;
    if (lane == 0) wsum[wid] = e;
    __syncthreads();

    if (threadIdx.x == 0) {
        float bs = 0.0f;
        #pragma unroll
        for (int w = 0; w < BLOCK / 64; ++w) bs += wsum[w];
        atomicAdd(out, bs);
    }
}

extern "C" void kernel_launch(void* const* d_in, const int* in_sizes, int n_in,
                              void* d_out, int out_size, void* d_ws, size_t ws_size,
                              hipStream_t stream) {
    const float* mean     = (const float*)d_in[0];
    const float* variance = (const float*)d_in[1];
    const float* noise    = (const float*)d_in[2];
    const float* target   = (const float*)d_in[3];
    float* out = (float*)d_out;

    // d_out is poisoned before timing and not re-zeroed between replays.
    hipMemsetAsync(out, 0, sizeof(float), stream);

    const int grid = BD / BLOCK;  // 2048 blocks
    energy_score_kernel<<<grid, BLOCK, 0, stream>>>(mean, variance, noise, target, out);
}